// Round 2
// baseline (1316.327 us; speedup 1.0000x reference)
//
#include <hip/hip_runtime.h>
#include <math.h>

#define HID 32
#define BS 256

// ---------------- structure-building kernels ----------------

__global__ void k_zero_i(int* __restrict__ p, int n) {
  int i = blockIdx.x * BS + threadIdx.x;
  if (i < n) p[i] = 0;
}

// cnt[dst]++ over M edges
__global__ void k_count(const int* __restrict__ ei, int* __restrict__ cnt, int M) {
  int e = blockIdx.x * BS + threadIdx.x;
  if (e < M) atomicAdd(&cnt[ei[M + e]], 1);
}

// per-block sums of cnt -> bsum[NB]
__global__ void k_bsum(const int* __restrict__ cnt, int* __restrict__ bsum, int T) {
  __shared__ int s[BS];
  int i = blockIdx.x * BS + threadIdx.x;
  s[threadIdx.x] = (i < T) ? cnt[i] : 0;
  __syncthreads();
  for (int off = BS / 2; off > 0; off >>= 1) {
    if (threadIdx.x < off) s[threadIdx.x] += s[threadIdx.x + off];
    __syncthreads();
  }
  if (threadIdx.x == 0) bsum[blockIdx.x] = s[0];
}

// single-block exclusive scan of bsum[0..NB) -> boff[0..NB)
__global__ void k_scanb(const int* __restrict__ bsum, int* __restrict__ boff, int NB) {
  __shared__ int buf[BS];
  __shared__ int run;
  if (threadIdx.x == 0) run = 0;
  __syncthreads();
  for (int base = 0; base < NB; base += BS) {
    int i = base + threadIdx.x;
    int v = (i < NB) ? bsum[i] : 0;
    buf[threadIdx.x] = v;
    __syncthreads();
    for (int off = 1; off < BS; off <<= 1) {
      int t = buf[threadIdx.x];
      int u = (threadIdx.x >= off) ? buf[threadIdx.x - off] : 0;
      __syncthreads();
      buf[threadIdx.x] = t + u;
      __syncthreads();
    }
    int incl = buf[threadIdx.x];
    if (i < NB) boff[i] = run + incl - v;  // exclusive
    __syncthreads();
    if (threadIdx.x == BS - 1) run += buf[BS - 1];
    __syncthreads();
  }
}

// row_ptr[i] = boff[blk] + in-block exclusive scan of cnt; row_ptr[T] = M
__global__ void k_scan3(const int* __restrict__ cnt, const int* __restrict__ boff,
                        int* __restrict__ row_ptr, int T, int M) {
  __shared__ int buf[BS];
  int i = blockIdx.x * BS + threadIdx.x;
  int v = (i < T) ? cnt[i] : 0;
  buf[threadIdx.x] = v;
  __syncthreads();
  for (int off = 1; off < BS; off <<= 1) {
    int t = buf[threadIdx.x];
    int u = (threadIdx.x >= off) ? buf[threadIdx.x - off] : 0;
    __syncthreads();
    buf[threadIdx.x] = t + u;
    __syncthreads();
  }
  int incl = buf[threadIdx.x];
  if (i < T) row_ptr[i] = boff[blockIdx.x] + incl - v;
  if (i == 0) row_ptr[T] = M;
}

__global__ void k_copy_i(const int* __restrict__ a, int* __restrict__ b, int n) {
  int i = blockIdx.x * BS + threadIdx.x;
  if (i < n) b[i] = a[i];
}

// scatter src indices into CSR order by dst
__global__ void k_fill(const int* __restrict__ ei, int* __restrict__ cursor,
                       int* __restrict__ srt, int M) {
  int e = blockIdx.x * BS + threadIdx.x;
  if (e >= M) return;
  int s = ei[e], d = ei[M + e];
  int pos = atomicAdd(&cursor[d], 1);
  srt[pos] = s;
}

// dis[i] = rsqrt(deg_i + 1), deg from row_ptr
__global__ void k_dis(const int* __restrict__ row_ptr, float* __restrict__ dis, int T) {
  int i = blockIdx.x * BS + threadIdx.x;
  if (i < T) dis[i] = rsqrtf((float)(row_ptr[i + 1] - row_ptr[i]) + 1.0f);
}

// ---------------- math kernels ----------------

// step 1: tri4[i] = (t12 + ec[c12]/cnt[c12], t13 + ..., t23 + ..., 0)
__global__ void k_step1pack(const float* __restrict__ ec,
                            const float* __restrict__ t12, const float* __restrict__ t13,
                            const float* __restrict__ t23,
                            const int* __restrict__ c12, const int* __restrict__ c13,
                            const int* __restrict__ c23,
                            const float* __restrict__ cnt,
                            float4* __restrict__ tri4, int T) {
  int i = blockIdx.x * BS + threadIdx.x;
  if (i >= T) return;
  int a = c12[i], b = c13[i], c = c23[i];
  float4 v;
  v.x = t12[i] + ec[a] / cnt[a];
  v.y = t13[i] + ec[b] / cnt[b];
  v.z = t23[i] + ec[c] / cnt[c];
  v.w = 0.0f;
  tri4[i] = v;
}

// out_ec init: where(cnt>0, 0, ec)
__global__ void k_initec(const float* __restrict__ ec, const float* __restrict__ cnt,
                         float* __restrict__ oec, int E) {
  int i = blockIdx.x * BS + threadIdx.x;
  if (i < E) oec[i] = (cnt[i] > 0.0f) ? 0.0f : ec[i];
}

// layer-1 aggregate in the 3-channel domain: G4[i] = sum_in tri4[s]*dis_s*dis_i + tri4[i]*dis_i^2
__global__ __launch_bounds__(BS) void k_agg1(const int* __restrict__ row_ptr,
                                             const int* __restrict__ srt,
                                             const float* __restrict__ dis,
                                             const float4* __restrict__ tri4,
                                             float4* __restrict__ G4, int T) {
  int i = blockIdx.x * BS + threadIdx.x;
  if (i >= T) return;
  int r0 = row_ptr[i], r1 = row_ptr[i + 1];
  float di = dis[i];
  float4 ts = tri4[i];
  float d2 = di * di;
  float ax = ts.x * d2, ay = ts.y * d2, az = ts.z * d2;
  for (int e = r0; e < r1; ++e) {
    int s = srt[e];
    float w = di * dis[s];
    float4 v = tri4[s];
    ax = fmaf(v.x, w, ax);
    ay = fmaf(v.y, w, ay);
    az = fmaf(v.z, w, az);
  }
  float4 o;
  o.x = ax; o.y = ay; o.z = az; o.w = 0.0f;
  G4[i] = o;
}

// fused: layer-1 transform (W1,b1,relu on the fly) -> layer-2 aggregate in registers
//        -> x2 = relu(agg@W2+b2) -> delta = x2@Wout+bout -> t updates + edge scatter
__global__ __launch_bounds__(BS) void k_l2head(
    const int* __restrict__ row_ptr, const int* __restrict__ srt,
    const float* __restrict__ dis, const float4* __restrict__ G4,
    const float4* __restrict__ tri4,
    const float* __restrict__ W1, const float* __restrict__ b1,
    const float* __restrict__ W2, const float* __restrict__ b2,
    const float* __restrict__ Wout, const float* __restrict__ bout,
    const int* __restrict__ c12, const int* __restrict__ c13,
    const int* __restrict__ c23,
    float* __restrict__ o12, float* __restrict__ o13, float* __restrict__ o23,
    float* __restrict__ oec, int T) {
  __shared__ float w1s[3 * HID];
  __shared__ float b1s[HID];
  __shared__ float w2s[HID * HID];
  __shared__ float b2s[HID];
  __shared__ float wos[HID * 3];
  __shared__ float bos[3];
  for (int j = threadIdx.x; j < 3 * HID; j += BS) w1s[j] = W1[j];
  for (int j = threadIdx.x; j < HID; j += BS) b1s[j] = b1[j];
  for (int j = threadIdx.x; j < HID * HID; j += BS) w2s[j] = W2[j];
  for (int j = threadIdx.x; j < HID; j += BS) b2s[j] = b2[j];
  for (int j = threadIdx.x; j < HID * 3; j += BS) wos[j] = Wout[j];
  if (threadIdx.x < 3) bos[threadIdx.x] = bout[threadIdx.x];
  __syncthreads();

  int i = blockIdx.x * BS + threadIdx.x;
  if (i >= T) return;
  int r0 = row_ptr[i], r1 = row_ptr[i + 1];
  float di = dis[i];
  float d2 = di * di;

  // layer-2 aggregate in registers; h1 recomputed on the fly from G4
  float acc[HID];
  {
    float4 g = G4[i];
#pragma unroll
    for (int h = 0; h < HID; ++h) {
      float v = fmaf(g.x, w1s[h], fmaf(g.y, w1s[HID + h], fmaf(g.z, w1s[2 * HID + h], b1s[h])));
      acc[h] = fmaxf(v, 0.0f) * d2;  // self-loop term
    }
  }
  for (int e = r0; e < r1; ++e) {
    int s = srt[e];
    float w = di * dis[s];
    float4 g = G4[s];
#pragma unroll
    for (int h = 0; h < HID; ++h) {
      float v = fmaf(g.x, w1s[h], fmaf(g.y, w1s[HID + h], fmaf(g.z, w1s[2 * HID + h], b1s[h])));
      acc[h] = fmaf(fmaxf(v, 0.0f), w, acc[h]);
    }
  }

  // x2 = relu(acc @ W2 + b2); delta = x2 @ Wout + bout  (x2 never stored)
  float d0 = bos[0], d1 = bos[1], dd2 = bos[2];
  for (int hp = 0; hp < HID; ++hp) {
    float v = b2s[hp];
#pragma unroll
    for (int h = 0; h < HID; ++h) v = fmaf(acc[h], w2s[h * HID + hp], v);
    v = fmaxf(v, 0.0f);
    d0 = fmaf(v, wos[hp * 3 + 0], d0);
    d1 = fmaf(v, wos[hp * 3 + 1], d1);
    dd2 = fmaf(v, wos[hp * 3 + 2], dd2);
  }

  float4 tp = tri4[i];
  o12[i] = tp.x - d0;
  o13[i] = tp.y - d1;
  o23[i] = tp.z - dd2;
  unsafeAtomicAdd(&oec[c12[i]], d0);
  unsafeAtomicAdd(&oec[c13[i]], d1);
  unsafeAtomicAdd(&oec[c23[i]], dd2);
}

// ---------------- launch ----------------

extern "C" void kernel_launch(void* const* d_in, const int* in_sizes, int n_in,
                              void* d_out, int out_size, void* d_ws, size_t ws_size,
                              hipStream_t stream) {
  const float* ec  = (const float*)d_in[0];
  const float* t12 = (const float*)d_in[1];
  const float* t13 = (const float*)d_in[2];
  const float* t23 = (const float*)d_in[3];
  const int* c12   = (const int*)d_in[4];
  const int* c13   = (const int*)d_in[5];
  const int* c23   = (const int*)d_in[6];
  const float* cnt = (const float*)d_in[7];
  const int* ei    = (const int*)d_in[8];
  const float* W1  = (const float*)d_in[9];
  const float* b1  = (const float*)d_in[10];
  const float* W2  = (const float*)d_in[11];
  const float* b2  = (const float*)d_in[12];
  const float* Wout = (const float*)d_in[13];
  const float* bout = (const float*)d_in[14];

  const int E = in_sizes[0];
  const int T = in_sizes[1];
  const int M = in_sizes[8] / 2;
  const int NB = (T + BS - 1) / BS;

  float* oec = (float*)d_out;
  float* o12 = oec + E;
  float* o13 = o12 + T;
  float* o23 = o13 + T;

  // workspace (floats/ints, 4B each), ~112 MB total:
  // tri4[4T] | G4[4T] | dis[T] | cnt[T] | row_ptr[T+1] | cursor[T] | srt[M] | bsum[NB] | boff[NB]
  float4* tri4 = (float4*)d_ws;
  float4* G4   = tri4 + T;
  float*  dis  = (float*)(G4 + T);
  int*    icnt = (int*)(dis + T);
  int*    rptr = icnt + T;
  int*    curs = rptr + (T + 1);
  int*    srt  = curs + T;
  int*    bsum = srt + M;
  int*    boff = bsum + NB;

  auto blocks = [](long n) { return (int)((n + BS - 1) / BS); };

  // build CSR (counting sort by dst)
  k_zero_i<<<blocks(T), BS, 0, stream>>>(icnt, T);
  k_count<<<blocks(M), BS, 0, stream>>>(ei, icnt, M);
  k_bsum<<<NB, BS, 0, stream>>>(icnt, bsum, T);
  k_scanb<<<1, BS, 0, stream>>>(bsum, boff, NB);
  k_scan3<<<NB, BS, 0, stream>>>(icnt, boff, rptr, T, M);
  k_copy_i<<<blocks(T), BS, 0, stream>>>(rptr, curs, T);
  k_fill<<<blocks(M), BS, 0, stream>>>(ei, curs, srt, M);
  k_dis<<<blocks(T), BS, 0, stream>>>(rptr, dis, T);

  // step 1 (edge->triplet messages), packed for float4 gathers
  k_step1pack<<<blocks(T), BS, 0, stream>>>(ec, t12, t13, t23, c12, c13, c23, cnt, tri4, T);

  // layer 1 aggregate in 3-channel domain
  k_agg1<<<blocks(T), BS, 0, stream>>>(rptr, srt, dis, tri4, G4, T);

  // output edge costs init, then fused layer2 + head + scatter
  k_initec<<<blocks(E), BS, 0, stream>>>(ec, cnt, oec, E);
  k_l2head<<<blocks(T), BS, 0, stream>>>(rptr, srt, dis, G4, tri4,
                                         W1, b1, W2, b2, Wout, bout,
                                         c12, c13, c23, o12, o13, o23, oec, T);
}

// Round 3
// 1110.378 us; speedup vs baseline: 1.1855x; 1.1855x over previous
//
#include <hip/hip_runtime.h>
#include <math.h>

#define HID 32
#define BS 256

// ---------------- structure-building kernels ----------------

__global__ void k_zero_i(int* __restrict__ p, int n) {
  int i = blockIdx.x * BS + threadIdx.x;
  if (i < n) p[i] = 0;
}

// cnt[dst]++ over M edges
__global__ void k_count(const int* __restrict__ ei, int* __restrict__ cnt, int M) {
  int e = blockIdx.x * BS + threadIdx.x;
  if (e < M) atomicAdd(&cnt[ei[M + e]], 1);
}

// per-block sums of cnt -> bsum[NB]
__global__ void k_bsum(const int* __restrict__ cnt, int* __restrict__ bsum, int T) {
  __shared__ int s[BS];
  int i = blockIdx.x * BS + threadIdx.x;
  s[threadIdx.x] = (i < T) ? cnt[i] : 0;
  __syncthreads();
  for (int off = BS / 2; off > 0; off >>= 1) {
    if (threadIdx.x < off) s[threadIdx.x] += s[threadIdx.x + off];
    __syncthreads();
  }
  if (threadIdx.x == 0) bsum[blockIdx.x] = s[0];
}

// single-block exclusive scan of bsum[0..NB) -> boff[0..NB)
__global__ void k_scanb(const int* __restrict__ bsum, int* __restrict__ boff, int NB) {
  __shared__ int buf[BS];
  __shared__ int run;
  if (threadIdx.x == 0) run = 0;
  __syncthreads();
  for (int base = 0; base < NB; base += BS) {
    int i = base + threadIdx.x;
    int v = (i < NB) ? bsum[i] : 0;
    buf[threadIdx.x] = v;
    __syncthreads();
    for (int off = 1; off < BS; off <<= 1) {
      int t = buf[threadIdx.x];
      int u = (threadIdx.x >= off) ? buf[threadIdx.x - off] : 0;
      __syncthreads();
      buf[threadIdx.x] = t + u;
      __syncthreads();
    }
    int incl = buf[threadIdx.x];
    if (i < NB) boff[i] = run + incl - v;  // exclusive
    __syncthreads();
    if (threadIdx.x == BS - 1) run += buf[BS - 1];
    __syncthreads();
  }
}

// row_ptr[i] = boff[blk] + in-block exclusive scan of cnt; row_ptr[T] = M
__global__ void k_scan3(const int* __restrict__ cnt, const int* __restrict__ boff,
                        int* __restrict__ row_ptr, int T, int M) {
  __shared__ int buf[BS];
  int i = blockIdx.x * BS + threadIdx.x;
  int v = (i < T) ? cnt[i] : 0;
  buf[threadIdx.x] = v;
  __syncthreads();
  for (int off = 1; off < BS; off <<= 1) {
    int t = buf[threadIdx.x];
    int u = (threadIdx.x >= off) ? buf[threadIdx.x - off] : 0;
    __syncthreads();
    buf[threadIdx.x] = t + u;
    __syncthreads();
  }
  int incl = buf[threadIdx.x];
  if (i < T) row_ptr[i] = boff[blockIdx.x] + incl - v;
  if (i == 0) row_ptr[T] = M;
}

__global__ void k_copy_i(const int* __restrict__ a, int* __restrict__ b, int n) {
  int i = blockIdx.x * BS + threadIdx.x;
  if (i < n) b[i] = a[i];
}

// scatter src indices into CSR order by dst
__global__ void k_fill(const int* __restrict__ ei, int* __restrict__ cursor,
                       int* __restrict__ srt, int M) {
  int e = blockIdx.x * BS + threadIdx.x;
  if (e >= M) return;
  int s = ei[e], d = ei[M + e];
  int pos = atomicAdd(&cursor[d], 1);
  srt[pos] = s;
}

// ---------------- math kernels ----------------

// msg[e] = ec[e]/cnt[e]  (shrinks step-1 gather target to one 4MB array)
__global__ void k_msg(const float* __restrict__ ec, const float* __restrict__ cnt,
                      float* __restrict__ msg, int E) {
  int i = blockIdx.x * BS + threadIdx.x;
  if (i < E) msg[i] = ec[i] / cnt[i];
}

// step 1: tri4[i] = (t12 + msg[c12], t13 + msg[c13], t23 + msg[c23], dis_i)
// dis_i computed inline from row_ptr (deg+1)^-1/2 — packed into .w so the
// per-edge gather in k_agg1 needs only ONE random cacheline.
__global__ void k_step1pack(const float* __restrict__ msg,
                            const float* __restrict__ t12, const float* __restrict__ t13,
                            const float* __restrict__ t23,
                            const int* __restrict__ c12, const int* __restrict__ c13,
                            const int* __restrict__ c23,
                            const int* __restrict__ row_ptr,
                            float4* __restrict__ tri4, int T) {
  int i = blockIdx.x * BS + threadIdx.x;
  if (i >= T) return;
  int a = c12[i], b = c13[i], c = c23[i];
  float4 v;
  v.x = t12[i] + msg[a];
  v.y = t13[i] + msg[b];
  v.z = t23[i] + msg[c];
  v.w = rsqrtf((float)(row_ptr[i + 1] - row_ptr[i]) + 1.0f);
  tri4[i] = v;
}

// out_ec init: where(cnt>0, 0, ec)
__global__ void k_initec(const float* __restrict__ ec, const float* __restrict__ cnt,
                         float* __restrict__ oec, int E) {
  int i = blockIdx.x * BS + threadIdx.x;
  if (i < E) oec[i] = (cnt[i] > 0.0f) ? 0.0f : ec[i];
}

// layer-1 aggregate in the 3-channel domain.
// G4[i].xyz = sum_in tri4[s].xyz * dis_s*dis_i + tri4[i].xyz*dis_i^2 ; G4[i].w = dis_i
// dis_s comes from the gathered tri4[s].w -> one random line per edge.
__global__ __launch_bounds__(BS) void k_agg1(const int* __restrict__ row_ptr,
                                             const int* __restrict__ srt,
                                             const float4* __restrict__ tri4,
                                             float4* __restrict__ G4, int T) {
  int i = blockIdx.x * BS + threadIdx.x;
  if (i >= T) return;
  int r0 = row_ptr[i], r1 = row_ptr[i + 1];
  float4 ts = tri4[i];
  float di = ts.w;
  float d2 = di * di;
  float ax = ts.x * d2, ay = ts.y * d2, az = ts.z * d2;
  for (int e = r0; e < r1; ++e) {
    int s = srt[e];
    float4 v = tri4[s];
    float w = v.w * di;
    ax = fmaf(v.x, w, ax);
    ay = fmaf(v.y, w, ay);
    az = fmaf(v.z, w, az);
  }
  float4 o;
  o.x = ax; o.y = ay; o.z = az; o.w = di;
  G4[i] = o;
}

// fused: layer-1 transform (W1,b1,relu on the fly) -> layer-2 aggregate in registers
//        -> x2 = relu(agg@W2+b2) -> delta = x2@Wout+bout -> t updates + edge scatter
// Per edge: ONE random 16B gather (G4[s]); dis_s = G4[s].w.
__global__ __launch_bounds__(BS) void k_l2head(
    const int* __restrict__ row_ptr, const int* __restrict__ srt,
    const float4* __restrict__ G4, const float4* __restrict__ tri4,
    const float* __restrict__ W1, const float* __restrict__ b1,
    const float* __restrict__ W2, const float* __restrict__ b2,
    const float* __restrict__ Wout, const float* __restrict__ bout,
    const int* __restrict__ c12, const int* __restrict__ c13,
    const int* __restrict__ c23,
    float* __restrict__ o12, float* __restrict__ o13, float* __restrict__ o23,
    float* __restrict__ oec, int T) {
  __shared__ float w1s[3 * HID];
  __shared__ float b1s[HID];
  __shared__ float w2s[HID * HID];
  __shared__ float b2s[HID];
  __shared__ float wos[HID * 3];
  __shared__ float bos[3];
  for (int j = threadIdx.x; j < 3 * HID; j += BS) w1s[j] = W1[j];
  for (int j = threadIdx.x; j < HID; j += BS) b1s[j] = b1[j];
  for (int j = threadIdx.x; j < HID * HID; j += BS) w2s[j] = W2[j];
  for (int j = threadIdx.x; j < HID; j += BS) b2s[j] = b2[j];
  for (int j = threadIdx.x; j < HID * 3; j += BS) wos[j] = Wout[j];
  if (threadIdx.x < 3) bos[threadIdx.x] = bout[threadIdx.x];
  __syncthreads();

  int i = blockIdx.x * BS + threadIdx.x;
  if (i >= T) return;
  int r0 = row_ptr[i], r1 = row_ptr[i + 1];
  float4 gi = G4[i];
  float di = gi.w;
  float d2 = di * di;

  // layer-2 aggregate in registers; h1 recomputed on the fly from G4
  float acc[HID];
#pragma unroll
  for (int h = 0; h < HID; ++h) {
    float v = fmaf(gi.x, w1s[h], fmaf(gi.y, w1s[HID + h], fmaf(gi.z, w1s[2 * HID + h], b1s[h])));
    acc[h] = fmaxf(v, 0.0f) * d2;  // self-loop term
  }
  for (int e = r0; e < r1; ++e) {
    int s = srt[e];
    float4 g = G4[s];
    float w = g.w * di;
#pragma unroll
    for (int h = 0; h < HID; ++h) {
      float v = fmaf(g.x, w1s[h], fmaf(g.y, w1s[HID + h], fmaf(g.z, w1s[2 * HID + h], b1s[h])));
      acc[h] = fmaf(fmaxf(v, 0.0f), w, acc[h]);
    }
  }

  // x2 = relu(acc @ W2 + b2); delta = x2 @ Wout + bout  (x2 never stored)
  float d0 = bos[0], d1 = bos[1], dd2 = bos[2];
  for (int hp = 0; hp < HID; ++hp) {
    float v = b2s[hp];
#pragma unroll
    for (int h = 0; h < HID; ++h) v = fmaf(acc[h], w2s[h * HID + hp], v);
    v = fmaxf(v, 0.0f);
    d0 = fmaf(v, wos[hp * 3 + 0], d0);
    d1 = fmaf(v, wos[hp * 3 + 1], d1);
    dd2 = fmaf(v, wos[hp * 3 + 2], dd2);
  }

  float4 tp = tri4[i];
  o12[i] = tp.x - d0;
  o13[i] = tp.y - d1;
  o23[i] = tp.z - dd2;
  unsafeAtomicAdd(&oec[c12[i]], d0);
  unsafeAtomicAdd(&oec[c13[i]], d1);
  unsafeAtomicAdd(&oec[c23[i]], dd2);
}

// ---------------- launch ----------------

extern "C" void kernel_launch(void* const* d_in, const int* in_sizes, int n_in,
                              void* d_out, int out_size, void* d_ws, size_t ws_size,
                              hipStream_t stream) {
  const float* ec  = (const float*)d_in[0];
  const float* t12 = (const float*)d_in[1];
  const float* t13 = (const float*)d_in[2];
  const float* t23 = (const float*)d_in[3];
  const int* c12   = (const int*)d_in[4];
  const int* c13   = (const int*)d_in[5];
  const int* c23   = (const int*)d_in[6];
  const float* cnt = (const float*)d_in[7];
  const int* ei    = (const int*)d_in[8];
  const float* W1  = (const float*)d_in[9];
  const float* b1  = (const float*)d_in[10];
  const float* W2  = (const float*)d_in[11];
  const float* b2  = (const float*)d_in[12];
  const float* Wout = (const float*)d_in[13];
  const float* bout = (const float*)d_in[14];

  const int E = in_sizes[0];
  const int T = in_sizes[1];
  const int M = in_sizes[8] / 2;
  const int NB = (T + BS - 1) / BS;

  float* oec = (float*)d_out;
  float* o12 = oec + E;
  float* o13 = o12 + T;
  float* o23 = o13 + T;

  // workspace (4B units), ~104 MB total:
  // tri4[4T] | G4[4T] | msg[E] | icnt[T] | row_ptr[T+1] | cursor[T] | srt[M] | bsum[NB] | boff[NB]
  float4* tri4 = (float4*)d_ws;
  float4* G4   = tri4 + T;
  float*  msg  = (float*)(G4 + T);
  int*    icnt = (int*)(msg + E);
  int*    rptr = icnt + T;
  int*    curs = rptr + (T + 1);
  int*    srt  = curs + T;
  int*    bsum = srt + M;
  int*    boff = bsum + NB;

  auto blocks = [](long n) { return (int)((n + BS - 1) / BS); };

  // build CSR (counting sort by dst)
  k_zero_i<<<blocks(T), BS, 0, stream>>>(icnt, T);
  k_count<<<blocks(M), BS, 0, stream>>>(ei, icnt, M);
  k_bsum<<<NB, BS, 0, stream>>>(icnt, bsum, T);
  k_scanb<<<1, BS, 0, stream>>>(bsum, boff, NB);
  k_scan3<<<NB, BS, 0, stream>>>(icnt, boff, rptr, T, M);
  k_copy_i<<<blocks(T), BS, 0, stream>>>(rptr, curs, T);
  k_fill<<<blocks(M), BS, 0, stream>>>(ei, curs, srt, M);

  // step 1 (edge->triplet messages), packed with dis in .w
  k_msg<<<blocks(E), BS, 0, stream>>>(ec, cnt, msg, E);
  k_step1pack<<<blocks(T), BS, 0, stream>>>(msg, t12, t13, t23, c12, c13, c23,
                                            rptr, tri4, T);

  // layer 1 aggregate in 3-channel domain
  k_agg1<<<blocks(T), BS, 0, stream>>>(rptr, srt, tri4, G4, T);

  // output edge costs init, then fused layer2 + head + scatter
  k_initec<<<blocks(E), BS, 0, stream>>>(ec, cnt, oec, E);
  k_l2head<<<blocks(T), BS, 0, stream>>>(rptr, srt, G4, tri4,
                                         W1, b1, W2, b2, Wout, bout,
                                         c12, c13, c23, o12, o13, o23, oec, T);
}